// Round 14
// baseline (145.044 us; speedup 1.0000x reference)
//
#include <hip/hip_runtime.h>
#include <hip/hip_bf16.h>

// Shapes: B=2, C=256, H=W=24 (HW=576), G=16, Cg=16, GRID=25, AC=6400, Mg=400
// Inputs fp32, output fp32.
// ws layout: h1b (bf16 ushort)[4,718,592] | ph0 f32[204,800] | ph1 f32[204,800]
// Harness floor: d_ws 0xAA fill ~42 us/iter + aux dispatches. Kernel time only.
// LESSON (R9): per-lane arrays indexed ONLY by compile-time constants.
// LESSON (R11): m-split duplicates phase 1 — split by pixels.
// LESSON (R12): >=6 MFMA per phase-2 strip or fixed costs dominate.

typedef __attribute__((ext_vector_type(8))) short short8;
typedef __attribute__((ext_vector_type(4))) float f32x4;

static __device__ __forceinline__ unsigned short f2bf(float x) {
    unsigned u = __float_as_uint(x);
    unsigned r = (u + 0x7fffu + ((u >> 16) & 1u)) >> 16;   // RNE
    return (unsigned short)r;
}

// LDS map (fully disjoint -> ONE barrier), 40448 B -> 4 blocks/CU:
//  xs  [cell lr14 x col26][ci p16] @0      (11648 B)  bf16 padded image slab
//  wA  [kk5][co16][k32]            @11648  (5120 B)   W1*scale, K-padded
//  hsb [s288][j16]                 @16768  (9216 B)   phase-1 out, bf16
//  wlb [m400][j16]                 @25984  (12800 B)  W2*scale, bf16
//  bias2 [m400] f32                @38784  (1600 B)
//  bias1 [16] f32                  @40384  (64 B)
//  zpad: aliases xs cell(0,0) — always zero for both hsels (row0|col0 pad)
#define XS_OFF   0
#define WA_OFF   11648
#define HS_OFF   16768
#define WLB_OFF  25984
#define B2_OFF   38784
#define BB1_OFF  40384
#define ZP_OFF   0
#define SMEM_BYTES 40448

// Grid 1024: bid = hsel*512 + (i*32 + b*16 + g); hsel = pixel half (12 rows).
// 192 threads = 3 waves x 6 pixel-tiles.
__global__ __launch_bounds__(192, 3) void k12_fused(
    const float* __restrict__ xin,
    const float* __restrict__ W1,
    const float* __restrict__ g1, const float* __restrict__ b1,
    const float* __restrict__ m1, const float* __restrict__ v1,
    const float* __restrict__ W2,
    const float* __restrict__ g2, const float* __restrict__ b2,
    const float* __restrict__ m2, const float* __restrict__ v2,
    unsigned short* __restrict__ h1b,
    float* __restrict__ ph)                    // ph[hsel][204800], pre-zeroed
{
    __shared__ __align__(16) char smem[SMEM_BYTES];
    short* xs    = (short*)smem;
    short* wAp   = (short*)(smem + WA_OFF);
    short* hsb   = (short*)(smem + HS_OFF);
    short* wlb   = (short*)(smem + WLB_OFF);
    float* bias2 = (float*)(smem + B2_OFF);
    float* bias1 = (float*)(smem + BB1_OFF);

    int bid  = blockIdx.x;
    int hsel = bid >> 9;                       // 0/1: image rows 0-11 / 12-23
    int core = bid & 511;                      // i*32 + b*16 + g
    int i = core >> 5, b = (core >> 4) & 1, g = core & 15;
    int t = threadIdx.x;
    int r0 = hsel * 12;

    // ================== staging (everything before ONE barrier) =============
    // zero ONLY never-staged xs cells: full row zrow + col0 + col25 (54 cells)
    {
        int zrow = hsel ? 13 : 0;
        int* xz = (int*)xs;
        for (int idx = t; idx < 432; idx += 192) {
            int c = idx >> 3, j = idx & 7;
            int lr, col;
            if (c < 26) { lr = zrow; col = c; }
            else        { int cc = c - 26; lr = cc >> 1; col = (cc & 1) ? 25 : 0; }
            xz[(lr*26 + col)*8 + j] = 0;
        }
    }
    if (t < 16) {
        int c = i*256 + g*16 + t;
        float sc = g1[c] * rsqrtf(v1[c] + 1e-5f);
        bias1[t] = b1[c] - m1[c] * sc;
    }
    // image interior: rows r0-1 .. r0+12 clipped; cell lr = r-r0+1, col = x+1
    {
        const float* xb = &xin[(b*256 + g*16)*576];
        for (int idx = t; idx < 5376; idx += 192) {
            int ci = idx / 336; int rem = idx - ci*336;
            int lr = rem / 24;  int x = rem - lr*24;
            int r = r0 + lr - 1;
            if ((unsigned)r < 24u)
                xs[(lr*26 + x + 1)*16 + ci] = (short)f2bf(xb[ci*576 + r*24 + x]);
        }
    }
    // W1 * scale (scale inlined), K padded 144->160
    {
        const float* wb = &W1[(i*256 + g*16)*144];    // [co][ci][9]
        for (int idx = t; idx < 2560; idx += 192) {
            int kk = idx >> 9, rem = idx & 511, co = rem >> 5, k = rem & 31;
            int tap = 2*kk + (k >> 4), ci = k & 15;
            int c = i*256 + g*16 + co;
            float sc = g1[c] * rsqrtf(v1[c] + 1e-5f);
            float val = (tap < 9) ? wb[co*144 + ci*9 + tap] * sc : 0.f;
            wAp[(kk*16 + co)*32 + k] = (short)f2bf(val);
        }
    }
    // W2 * scale -> wlb, bias2
    for (int m = t; m < 400; m += 192) {
        int o = i*6400 + g*400 + m;
        float s2 = g2[o] * rsqrtf(v2[o] + 1e-5f);
        bias2[m] = b2[o] - m2[o] * s2;
        const float4* wr = (const float4*)&W2[o*16];
#pragma unroll
        for (int q = 0; q < 4; q++) {
            float4 wv = wr[q];
            wlb[m*16 + q*4 + 0] = (short)f2bf(wv.x * s2);
            wlb[m*16 + q*4 + 1] = (short)f2bf(wv.y * s2);
            wlb[m*16 + q*4 + 2] = (short)f2bf(wv.z * s2);
            wlb[m*16 + q*4 + 3] = (short)f2bf(wv.w * s2);
        }
    }
    __syncthreads();   // THE barrier

    int l = t & 63, w = t >> 6;                // 3 waves, 6 pixel-tiles each
    int quad = l >> 4, rc = l & 15;

    // ============ phase 1: D(16co x 288px) = W1'(16x144)*im2col + bias1 =====
    f32x4 dreg[6];
    {
        int ci0 = (quad & 1) * 8;
        short8 afr[5];
#pragma unroll
        for (int kk = 0; kk < 5; kk++)
            afr[kk] = *(const short8*)&wAp[(kk*16 + rc)*32 + quad*8];
        f32x4 cb1 = *(const f32x4*)&bias1[quad*4];

        // pitch 16, row stride 26*16=416; taps even (quads 0,1) / odd (2,3)
        const int offE[5] = {0, 32, 432, 832, 864};     // taps 0,2,4,6,8
        const int offO[5] = {16, 416, 448, 848, 848};   // taps 1,3,5,7,(9->A=0)
        int off[5];
#pragma unroll
        for (int kk = 0; kk < 5; kk++) off[kk] = (quad >= 2) ? offO[kk] : offE[kk];

#pragma unroll
        for (int tt = 0; tt < 6; tt++) {
            int sl = (w*6 + tt)*16 + rc;       // local pixel 0..287
            int ly = sl / 24; int x = sl - ly*24;
            int base = (ly*26 + x)*16 + ci0;
            f32x4 acc = cb1;
#pragma unroll
            for (int kk = 0; kk < 5; kk++) {
                short8 bf = *(const short8*)&xs[base + off[kk]];
                acc = __builtin_amdgcn_mfma_f32_16x16x32_bf16(afr[kk], bf, acc, 0, 0, 0);
            }
#pragma unroll
            for (int r = 0; r < 4; r++) acc[r] = fmaxf(acc[r], 0.f);
            dreg[tt] = acc;
        }
    }

    // h -> hsb (own rows; consumed intra-wave only) + h1b global (own data)
    {
        unsigned short* hout = &h1b[((i*2 + b)*256 + g*16)*576 + hsel*288];
#pragma unroll
        for (int tt = 0; tt < 6; tt++) {
            int sl = (w*6 + tt)*16 + rc;
            f32x4 acc = dreg[tt];
            unsigned short e0 = f2bf(acc[0]), e1 = f2bf(acc[1]);
            unsigned short e2 = f2bf(acc[2]), e3 = f2bf(acc[3]);
            uint2 pk = {(unsigned)e0 | ((unsigned)e1 << 16),
                        (unsigned)e2 | ((unsigned)e3 << 16)};
            *(uint2*)&hsb[sl*16 + quad*4] = pk;
            hout[(quad*4 + 0)*576 + sl] = e0;
            hout[(quad*4 + 1)*576 + sl] = e1;
            hout[(quad*4 + 2)*576 + sl] = e2;
            hout[(quad*4 + 3)*576 + sl] = e3;
        }
    }

    // ====== phase 2 (transposed): D2[s,m] = h(s,j)*W2'(j,m)+be[m]; relu, ====
    // row-sum, 2 shfl, global atomicAdd into this block's exclusive slice.
    {
        int qb = (quad & 1) * 16;              // byte offset of j-chunk
        short8 af2[6];
#pragma unroll
        for (int u = 0; u < 6; u++) {
            int boff = (l < 32) ? (HS_OFF + ((w*6 + u)*16 + rc)*32 + qb) : ZP_OFF;
            af2[u] = *(const short8*)(smem + boff);
        }
        const float inv = 1.f / 676.f;         // 26x26 pool incl. 100 border px
        float* pout = &ph[hsel*204800 + (i*2 + b)*6400 + g*400];
        bool bmaster = (hsel == 0) && (w == 0);
        for (int mt = 0; mt < 25; mt++) {
            int m0 = mt*16;
            int woff = (l < 32) ? (WLB_OFF + (m0 + rc)*32 + qb) : ZP_OFF;
            short8 wf = *(const short8*)(smem + woff);
            float be = bias2[m0 + rc];
            f32x4 cb = {be, be, be, be};       // bias per column m

            f32x4 accv = {0.f, 0.f, 0.f, 0.f};
#pragma unroll
            for (int u = 0; u < 6; u++) {
                f32x4 d = __builtin_amdgcn_mfma_f32_16x16x32_bf16(af2[u], wf, cb, 0, 0, 0);
#pragma unroll
                for (int r = 0; r < 4; r++)
                    accv[r] += fmaxf(d[r], 0.f);
            }
            float a = (accv[0] + accv[1]) + (accv[2] + accv[3]);
            a += __shfl_xor(a, 16);            // 4 quads = the tile's 16 rows
            a += __shfl_xor(a, 32);
            if (bmaster) a += 100.f * fmaxf(be, 0.f);
            if (l < 16)
                atomicAdd(&pout[m0 + l], a * inv);  // 3 waves/addr contention
        }
    }
}

// k3+k4 merged: recompute aff per block from the two pooled halves, then the
// output contraction over bf16 h.  bid = i*32 + q*16 + cg.
__global__ __launch_bounds__(256) void k34_out(const float* __restrict__ ph,
                                               const unsigned short* __restrict__ h1b,
                                               float* __restrict__ out)
{
    __shared__ float parts[256];
    __shared__ float av[2][16];
    int bid = blockIdx.x;
    int i = bid >> 5, q = (bid >> 4) & 1, cg = bid & 15;
    int t = threadIdx.x;

    // aff(i,p,l) = (1/16) sum_m P[i,p][i*400+m] * P[i,p][l*400+m],
    // P = ph0 + ph1
    {
        int pl = t >> 3;                 // 0..31 = p*16 + l
        int u  = t & 7;                  // 8 threads per dot
        int p = pl >> 4, lidx = pl & 15;
        const float* pb0 = &ph[(i*2 + p)*6400];
        const float* pb1 = pb0 + 204800;
        const float* t0 = &pb0[i*400];    const float* t1 = &pb1[i*400];
        const float* l0 = &pb0[lidx*400]; const float* l1 = &pb1[lidx*400];
        float s = 0.f;
        for (int m = u*50; m < u*50 + 50; m++)
            s = fmaf(t0[m] + t1[m], l0[m] + l1[m], s);
        parts[t] = s;
    }
    __syncthreads();
    if (t < 32) {
        float s = 0.f;
#pragma unroll
        for (int u = 0; u < 8; u++) s += parts[t*8 + u];
        av[t >> 4][t & 15] = s * (1.f/16.f);
    }
    __syncthreads();

    const unsigned short* hb = &h1b[((i*2 + q)*256 + cg)*576];
    int ch = i*32 + q*16 + cg;
    for (int s = t; s < 576; s += 256) {
        float acc0 = 0.f, acc1 = 0.f;
#pragma unroll
        for (int k = 0; k < 16; k++) {
            float v = __uint_as_float((unsigned)hb[k*9216 + s] << 16);
            acc0 = fmaf(av[0][k], v, acc0);
            acc1 = fmaf(av[1][k], v, acc1);
        }
        out[ch*576 + s]         = acc0;
        out[(512 + ch)*576 + s] = acc1;
    }
}

extern "C" void kernel_launch(void* const* d_in, const int* in_sizes, int n_in,
                              void* d_out, int out_size, void* d_ws, size_t ws_size,
                              hipStream_t stream)
{
    const float* x  = (const float*)d_in[0];
    const float* W1 = (const float*)d_in[1];
    const float* g1 = (const float*)d_in[2];
    const float* b1 = (const float*)d_in[3];
    const float* m1 = (const float*)d_in[4];
    const float* v1 = (const float*)d_in[5];
    const float* W2 = (const float*)d_in[6];
    const float* g2 = (const float*)d_in[7];
    const float* b2 = (const float*)d_in[8];
    const float* m2 = (const float*)d_in[9];
    const float* v2 = (const float*)d_in[10];

    unsigned short* h1b = (unsigned short*)d_ws;          // 4,718,592 ushorts
    float* ph = (float*)(h1b + 16*2*256*576);             // 2 x 204,800 floats

    float* out = (float*)d_out;

    // zero both pooled halves (graph-capturable async memset, 1.6 MB)
    hipMemsetAsync(ph, 0, 2*204800*sizeof(float), stream);

    hipLaunchKernelGGL(k12_fused, dim3(1024), dim3(192), 0, stream,
                       x, W1, g1, b1, m1, v1, W2, g2, b2, m2, v2, h1b, ph);
    hipLaunchKernelGGL(k34_out,   dim3(512),  dim3(256), 0, stream,
                       ph, h1b, out);
}

// Round 15
// 116.485 us; speedup vs baseline: 1.2452x; 1.2452x over previous
//
#include <hip/hip_runtime.h>
#include <hip/hip_bf16.h>

// Shapes: B=2, C=256, H=W=24 (HW=576), G=16, Cg=16, GRID=25, AC=6400, Mg=400
// Inputs fp32, output fp32.
// ws layout: h1b (bf16 ushort)[4,718,592] | pooled f32[204,800] | aff f32[512]
// Harness floor: d_ws 0xAA fill ~42 us/iter. dur_us ~= sum of dispatch durs.
// LESSON (R9): per-lane arrays indexed ONLY by compile-time constants.
// LESSON (R11): m-split duplicates phase 1 — split by pixels.
// LESSON (R12): >=6 MFMA per phase-2 strip or fixed costs dominate.
// LESSON (R14): keep xs/hsb pitch non-pow2 (24/20 shorts) — 32 B cells give
//   4-way LDS conflicts; precompute BN scale once, never per staged element.
// LESSON (R10-R14): merged k34 made 512 blocks redundantly recompute aff
//   (~16 us hidden regression) — keep k3 (32 blocks) and k4 (512) split.

typedef __attribute__((ext_vector_type(8))) short short8;
typedef __attribute__((ext_vector_type(4))) float f32x4;

static __device__ __forceinline__ unsigned short f2bf(float x) {
    unsigned u = __float_as_uint(x);
    unsigned r = (u + 0x7fffu + ((u >> 16) & 1u)) >> 16;   // RNE
    return (unsigned short)r;
}

// LDS byte-offset map (phase overlay):
//  phase1: xs [row27][col26][ci p24] @0 (33696) | wA [kk5][co16][k p40] @33696 (6400)
//  phase2: hsb [s576][j p20] @0 (23040) | wlb [m400][j16] @23040 (12800)
//          bias2 [m400] @35840 (1600) | pacc [m400] @37440 (1600)
//  zpad 16B @40096 | scale1 @40112 | bias1 @40176 | total 40240 -> 4 blk/CU
#define WA_OFF   33696
#define WLB_OFF  23040
#define B2_OFF   35840
#define PACC_OFF 37440
#define ZP_OFF   40096
#define S1_OFF   40112
#define BB1_OFF  40176
#define SMEM_BYTES 40240

__global__ __launch_bounds__(256) void k12_fused(
    const float* __restrict__ xin,
    const float* __restrict__ W1,
    const float* __restrict__ g1, const float* __restrict__ b1,
    const float* __restrict__ m1, const float* __restrict__ v1,
    const float* __restrict__ W2,
    const float* __restrict__ g2, const float* __restrict__ b2,
    const float* __restrict__ m2, const float* __restrict__ v2,
    unsigned short* __restrict__ h1b,
    float* __restrict__ pooled)
{
    __shared__ __align__(16) char smem[SMEM_BYTES];
    short* xs    = (short*)smem;
    short* wAp   = (short*)(smem + WA_OFF);
    short* hsb   = (short*)smem;
    short* wlb   = (short*)(smem + WLB_OFF);
    float* bias2 = (float*)(smem + B2_OFF);
    float* pacc  = (float*)(smem + PACC_OFF);
    float* scale1 = (float*)(smem + S1_OFF);
    float* bias1  = (float*)(smem + BB1_OFF);

    int bid = blockIdx.x;                      // i*32 + b*16 + g
    int i = bid >> 5, b = (bid >> 4) & 1, g = bid & 15;
    int t = threadIdx.x;

    // ---- phase 1 staging: zero pad regions, fold BN1 ----
    int* xz = (int*)xs;
    for (int idx = t; idx < 27*26*12; idx += 256) xz[idx] = 0;
    if (t < 4) ((int*)(smem + ZP_OFF))[t] = 0;
    if (t < 16) {
        int c = i*256 + g*16 + t;
        float sc = g1[c] * rsqrtf(v1[c] + 1e-5f);
        scale1[t] = sc;
        bias1[t]  = b1[c] - m1[c] * sc;
    }
    __syncthreads();

    const float* xb = &xin[(b*256 + g*16)*576];
    for (int idx = t; idx < 9216; idx += 256) {
        int ci = idx / 576; int s = idx - ci*576;
        int y = s / 24; int x = s - y*24;
        xs[((y+1)*26 + (x+1))*24 + ci] = (short)f2bf(xb[idx]);
    }
    const float* wb = &W1[(i*256 + g*16)*144];    // [co][ci][9]
    for (int idx = t; idx < 2560; idx += 256) {
        int kk = idx >> 9, rem = idx & 511, co = rem >> 5, k = rem & 31;
        int tap = 2*kk + (k >> 4), ci = k & 15;
        float val = (tap < 9) ? wb[co*144 + ci*9 + tap] * scale1[co] : 0.f;
        wAp[(kk*16 + co)*40 + k] = (short)f2bf(val);
    }
    __syncthreads();

    int l = t & 63, w = t >> 6;                // 4 waves, 9 pixel-tiles each
    int quad = l >> 4, rc = l & 15;

    // ---- phase 1 compute: D(16co x 576px) = W1'(16x144)*im2col + bias1 ----
    f32x4 dreg[9];
    {
        int ci0 = (quad & 1) * 8;
        short8 afr[5];
#pragma unroll
        for (int kk = 0; kk < 5; kk++)
            afr[kk] = *(const short8*)&wAp[(kk*16 + rc)*40 + quad*8];
        f32x4 cb1 = *(const f32x4*)&bias1[quad*4];

        const int offE[5] = {0, 48, 648, 1248, 1296};     // taps 0,2,4,6,8
        const int offO[5] = {24, 624, 672, 1272, 1872};   // taps 1,3,5,7,9
        int off[5];
#pragma unroll
        for (int kk = 0; kk < 5; kk++) off[kk] = (quad >= 2) ? offO[kk] : offE[kk];

#pragma unroll
        for (int tt = 0; tt < 9; tt++) {
            int s = (w*9 + tt)*16 + rc;
            int y = s / 24; int x = s - y*24;
            int base = (y*26 + x)*24 + ci0;
            f32x4 acc = cb1;
#pragma unroll
            for (int kk = 0; kk < 5; kk++) {
                short8 bf = *(const short8*)&xs[base + off[kk]];
                acc = __builtin_amdgcn_mfma_f32_16x16x32_bf16(afr[kk], bf, acc, 0, 0, 0);
            }
#pragma unroll
            for (int r = 0; r < 4; r++) acc[r] = fmaxf(acc[r], 0.f);
            dreg[tt] = acc;
        }
    }
    __syncthreads();   // all xs/wA reads done; safe to overlay hsb/wlb/bias2

    // write h to LDS (bf16 [s][j] pitch 20) + global bf16 channel-major
    {
        unsigned short* hout = &h1b[((i*2 + b)*256 + g*16)*576];
#pragma unroll
        for (int tt = 0; tt < 9; tt++) {
            int s = (w*9 + tt)*16 + rc;
            f32x4 acc = dreg[tt];
            unsigned short e0 = f2bf(acc[0]), e1 = f2bf(acc[1]);
            unsigned short e2 = f2bf(acc[2]), e3 = f2bf(acc[3]);
            unsigned p0 = (unsigned)e0 | ((unsigned)e1 << 16);
            unsigned p1 = (unsigned)e2 | ((unsigned)e3 << 16);
            uint2 pk = {p0, p1};
            *(uint2*)&hsb[s*20 + quad*4] = pk;
            hout[(quad*4 + 0)*576 + s] = e0;
            hout[(quad*4 + 1)*576 + s] = e1;
            hout[(quad*4 + 2)*576 + s] = e2;
            hout[(quad*4 + 3)*576 + s] = e3;
        }
    }

    // ---- phase 2 staging: W2*s2 -> wlb, bias2; zero pacc ----
    for (int m = t; m < 400; m += 256) {
        pacc[m] = 0.f;
        int o = i*6400 + g*400 + m;
        float s2 = g2[o] * rsqrtf(v2[o] + 1e-5f);
        bias2[m] = b2[o] - m2[o] * s2;
        const float4* wr = (const float4*)&W2[o*16];
#pragma unroll
        for (int q = 0; q < 4; q++) {
            float4 wv = wr[q];
            wlb[m*16 + q*4 + 0] = (short)f2bf(wv.x * s2);
            wlb[m*16 + q*4 + 1] = (short)f2bf(wv.y * s2);
            wlb[m*16 + q*4 + 2] = (short)f2bf(wv.z * s2);
            wlb[m*16 + q*4 + 3] = (short)f2bf(wv.w * s2);
        }
    }
    __syncthreads();

    // ---- phase 2 (transposed, registered A): D2[s,m] = h(s,j)*W2'(j,m)+be[m].
    // A = own 9 h-tiles (loaded once); B = W2 strip per mt. Pool = per-lane
    // row-sum of relu + 2 shfl -> LDS atomic pacc. ----
    {
        int q8 = (quad & 1) * 8;               // j-offset quads 0/1; 2/3 read zpad
        short8 af2[9];
#pragma unroll
        for (int u = 0; u < 9; u++) {
            int boff = (l < 32) ? ((((w*9 + u)*16 + rc)*20 + q8)*2) : ZP_OFF;
            af2[u] = *(const short8*)(smem + boff);
        }
        for (int mt = 0; mt < 25; mt++) {
            int m0 = mt*16;
            int woff = (l < 32) ? (WLB_OFF + ((m0 + rc)*16 + q8)*2) : ZP_OFF;
            short8 wf = *(const short8*)(smem + woff);
            float be = bias2[m0 + rc];
            f32x4 cb = {be, be, be, be};       // bias per column m

            f32x4 accv = {0.f, 0.f, 0.f, 0.f};
#pragma unroll
            for (int u = 0; u < 9; u++) {
                f32x4 d = __builtin_amdgcn_mfma_f32_16x16x32_bf16(af2[u], wf, cb, 0, 0, 0);
#pragma unroll
                for (int r = 0; r < 4; r++)
                    accv[r] += fmaxf(d[r], 0.f);
            }
            float a = (accv[0] + accv[1]) + (accv[2] + accv[3]);
            a += __shfl_xor(a, 16);            // sum 4 quads = 16 rows per tile
            a += __shfl_xor(a, 32);
            if (l < 16)
                atomicAdd(&pacc[m0 + l], a);   // ds_add_f32, 4 waves per addr
        }
    }
    __syncthreads();

    const float inv = 1.f / 676.f;             // 26x26 pool incl. 100 border px
    for (int m = t; m < 400; m += 256) {
        float be = bias2[m];
        pooled[(i*2+b)*6400 + g*400 + m] =
            (pacc[m] + 100.f * fmaxf(be, 0.f)) * inv;
    }
}

// k3: aff per (i,b) — 32 blocks only (aff computed ONCE, not per k4 block)
__global__ __launch_bounds__(256) void k3_aff(const float* __restrict__ pooled,
                                              float* __restrict__ aff)
{
    __shared__ float th[400];
    __shared__ float parts[256];
    int bid = blockIdx.x;           // i*2 + b
    int i = bid >> 1;
    int t = threadIdx.x;
    const float* pb = &pooled[bid*6400];
    for (int idx = t; idx < 400; idx += 256) th[idx] = pb[i*400 + idx];
    __syncthreads();
    int l = t >> 4, p = t & 15;
    float sum = 0.f;
    const float* pl = &pb[l*400];
    for (int m = p*25; m < p*25 + 25; m++) sum = fmaf(th[m], pl[m], sum);
    parts[t] = sum;
    __syncthreads();
    if (t < 16) {
        float s = 0.f;
        for (int pp = 0; pp < 16; pp++) s += parts[t*16 + pp];
        aff[bid*16 + t] = s * (1.f/16.f);
    }
}

// k4: output contraction over bf16 h, pair loads (uint = 2 px), float2 stores.
__global__ __launch_bounds__(256) void k4_out(const unsigned short* __restrict__ h1b,
                                              const float* __restrict__ aff,
                                              float* __restrict__ out)
{
    __shared__ float a0[16], a1[16];
    int bid = blockIdx.x;           // i*32 + q*16 + cg
    int i = bid >> 5, q = (bid >> 4) & 1, cg = bid & 15;
    int t = threadIdx.x;
    if (t < 16) a0[t] = aff[(i*2+0)*16 + t];
    else if (t < 32) a1[t-16] = aff[(i*2+1)*16 + (t-16)];
    __syncthreads();
    const unsigned short* hb = &h1b[((i*2+q)*256 + cg)*576];
    int ch = i*32 + q*16 + cg;
    for (int pp = t; pp < 288; pp += 256) {    // pixel pairs
        int s = pp*2;
        float acc0a = 0.f, acc0b = 0.f, acc1a = 0.f, acc1b = 0.f;
#pragma unroll
        for (int k = 0; k < 16; k++) {
            unsigned hv = *(const unsigned*)&hb[k*9216 + s];
            float va = __uint_as_float(hv << 16);
            float vb = __uint_as_float(hv & 0xffff0000u);
            acc0a = fmaf(a0[k], va, acc0a);
            acc0b = fmaf(a0[k], vb, acc0b);
            acc1a = fmaf(a1[k], va, acc1a);
            acc1b = fmaf(a1[k], vb, acc1b);
        }
        float2 o0 = {acc0a, acc0b};
        float2 o1 = {acc1a, acc1b};
        *(float2*)&out[ch*576 + s]         = o0;
        *(float2*)&out[(512 + ch)*576 + s] = o1;
    }
}

extern "C" void kernel_launch(void* const* d_in, const int* in_sizes, int n_in,
                              void* d_out, int out_size, void* d_ws, size_t ws_size,
                              hipStream_t stream)
{
    const float* x  = (const float*)d_in[0];
    const float* W1 = (const float*)d_in[1];
    const float* g1 = (const float*)d_in[2];
    const float* b1 = (const float*)d_in[3];
    const float* m1 = (const float*)d_in[4];
    const float* v1 = (const float*)d_in[5];
    const float* W2 = (const float*)d_in[6];
    const float* g2 = (const float*)d_in[7];
    const float* b2 = (const float*)d_in[8];
    const float* m2 = (const float*)d_in[9];
    const float* v2 = (const float*)d_in[10];

    unsigned short* h1b = (unsigned short*)d_ws;          // 4,718,592 ushorts
    float* pooled = (float*)(h1b + 16*2*256*576);         // 204,800 floats
    float* aff    = pooled + 204800;                      // 512 floats

    float* out = (float*)d_out;

    hipLaunchKernelGGL(k12_fused, dim3(512), dim3(256), 0, stream,
                       x, W1, g1, b1, m1, v1, W2, g2, b2, m2, v2, h1b, pooled);
    hipLaunchKernelGGL(k3_aff,    dim3(32),  dim3(256), 0, stream,
                       pooled, aff);
    hipLaunchKernelGGL(k4_out,    dim3(512), dim3(256), 0, stream,
                       h1b, aff, out);
}

// Round 16
// 116.377 us; speedup vs baseline: 1.2463x; 1.0009x over previous
//
#include <hip/hip_runtime.h>
#include <hip/hip_bf16.h>

// Shapes: B=2, C=256, H=W=24 (HW=576), G=16, Cg=16, GRID=25, AC=6400, Mg=400
// Inputs fp32, output fp32.
// ws layout: h1b (bf16 ushort)[4,718,592] | pooled f32[204,800] | aff f32[512]
// Harness floor: d_ws 0xAA fill ~41 us/iter + ~25 us aux dispatches/gaps.
// LESSON (R9): per-lane arrays indexed ONLY by compile-time constants.
// LESSON (R11): m-split duplicates phase 1 — split by pixels.
// LESSON (R12): >=6 MFMA per phase-2 strip or fixed costs dominate.
// LESSON (R14): non-pow2 LDS pitches (24/20 shorts); BN scale computed once.
// LESSON (R15): grid=512 -> 2 blocks/CU resident -> 80 KB LDS/block free.
//   De-overlay ALL LDS regions and barriers drop 5 -> 2 (phase1->phase2 needs
//   none: phase-2 A-frags are the wave's OWN phase-1 tiles, lgkmcnt-ordered).

typedef __attribute__((ext_vector_type(8))) short short8;
typedef __attribute__((ext_vector_type(4))) float f32x4;

static __device__ __forceinline__ unsigned short f2bf(float x) {
    unsigned u = __float_as_uint(x);
    unsigned r = (u + 0x7fffu + ((u >> 16) & 1u)) >> 16;   // RNE
    return (unsigned short)r;
}

// LDS byte-offset map — FULLY DISJOINT (79,280 B; 2 blocks/CU = 158.6 KB OK):
//  xs  [row27][col26][ci p24] @0      (33,696)  interior staged, 126 pad cells zeroed
//  wA  [kk5][co16][k p40]     @33,696 (6,400)   W1*scale, K-padded (finite => tap-9 safe)
//  hsb [s576][j p20]          @40,096 (23,040)  phase-1 out; own-wave write/read only
//  wlb [m400][j16]            @63,136 (12,800)  W2*scale
//  bias2 [m400]               @75,936 (1,600)
//  pacc  [m400]               @77,536 (1,600)   pool accumulator (ds atomics)
//  scale1 @79,136 (64) | bias1 @79,200 (64) | zpad 16B @79,264
#define WA_OFF   33696
#define HS_OFF   40096
#define WLB_OFF  63136
#define B2_OFF   75936
#define PACC_OFF 77536
#define S1_OFF   79136
#define BB1_OFF  79200
#define ZP_OFF   79264
#define SMEM_BYTES 79280

__global__ __launch_bounds__(256) void k12_fused(
    const float* __restrict__ xin,
    const float* __restrict__ W1,
    const float* __restrict__ g1, const float* __restrict__ b1,
    const float* __restrict__ m1, const float* __restrict__ v1,
    const float* __restrict__ W2,
    const float* __restrict__ g2, const float* __restrict__ b2,
    const float* __restrict__ m2, const float* __restrict__ v2,
    unsigned short* __restrict__ h1b,
    float* __restrict__ pooled)
{
    __shared__ __align__(16) char smem[SMEM_BYTES];
    short* xs    = (short*)smem;
    short* wAp   = (short*)(smem + WA_OFF);
    short* hsb   = (short*)(smem + HS_OFF);
    short* wlb   = (short*)(smem + WLB_OFF);
    float* bias2 = (float*)(smem + B2_OFF);
    float* pacc  = (float*)(smem + PACC_OFF);
    float* scale1 = (float*)(smem + S1_OFF);
    float* bias1  = (float*)(smem + BB1_OFF);

    int bid = blockIdx.x;                      // i*32 + b*16 + g
    int i = bid >> 5, b = (bid >> 4) & 1, g = bid & 15;
    int t = threadIdx.x;

    // ============== ALL staging before ONE barrier ==============
    // BN1 fold (wave 0 lanes; no barrier needed before W1 staging below
    // because W1 staging re-reads scale1 only after __syncthreads... no:
    // W1 staging needs scale1 NOW. Keep it dependency-free: compute sc
    // inline for W1 from a per-thread broadcast instead.)
    if (t < 16) {
        int c = i*256 + g*16 + t;
        float sc = g1[c] * rsqrtf(v1[c] + 1e-5f);
        scale1[t] = sc;
        bias1[t]  = b1[c] - m1[c] * sc;
    }
    // zero ONLY the 126 never-staged halo cells (rows 0,25,26 + cols 0,25)
    // + zpad; disjoint from interior staging -> no intervening barrier.
    {
        int* xz = (int*)xs;
        for (int idx = t; idx < 1512; idx += 256) {
            int c = idx / 12, j = idx - (idx / 12) * 12;
            int row, col;
            if (c < 26)      { row = 0;  col = c; }
            else if (c < 52) { row = 25; col = c - 26; }
            else if (c < 78) { row = 26; col = c - 52; }
            else { int k = c - 78; row = 1 + (k >> 1); col = (k & 1) ? 25 : 0; }
            xz[(row*26 + col)*12 + j] = 0;
        }
        if (t < 4) ((int*)(smem + ZP_OFF))[t] = 0;
    }
    // image interior (cells rows 1-24, cols 1-24)
    {
        const float* xb = &xin[(b*256 + g*16)*576];
        for (int idx = t; idx < 9216; idx += 256) {
            int ci = idx / 576; int s = idx - ci*576;
            int y = s / 24; int x = s - y*24;
            xs[((y+1)*26 + (x+1))*24 + ci] = (short)f2bf(xb[idx]);
        }
    }
    // W1 * scale (scale recomputed per (co) cheaply from globals to avoid a
    // scale1-dependency barrier: 16 rsqrt per 2560/256=10 iters is fine)
    {
        const float* wb = &W1[(i*256 + g*16)*144];    // [co][ci][9]
        for (int idx = t; idx < 2560; idx += 256) {
            int kk = idx >> 9, rem = idx & 511, co = rem >> 5, k = rem & 31;
            int tap = 2*kk + (k >> 4), ci = k & 15;
            int c = i*256 + g*16 + co;
            float sc = g1[c] * rsqrtf(v1[c] + 1e-5f);
            float val = (tap < 9) ? wb[co*144 + ci*9 + tap] * sc : 0.f;
            wAp[(kk*16 + co)*40 + k] = (short)f2bf(val);
        }
    }
    // W2 * scale -> wlb, bias2; zero pacc
    for (int m = t; m < 400; m += 256) {
        pacc[m] = 0.f;
        int o = i*6400 + g*400 + m;
        float s2 = g2[o] * rsqrtf(v2[o] + 1e-5f);
        bias2[m] = b2[o] - m2[o] * s2;
        const float4* wr = (const float4*)&W2[o*16];
#pragma unroll
        for (int q = 0; q < 4; q++) {
            float4 wv = wr[q];
            wlb[m*16 + q*4 + 0] = (short)f2bf(wv.x * s2);
            wlb[m*16 + q*4 + 1] = (short)f2bf(wv.y * s2);
            wlb[m*16 + q*4 + 2] = (short)f2bf(wv.z * s2);
            wlb[m*16 + q*4 + 3] = (short)f2bf(wv.w * s2);
        }
    }
    __syncthreads();                           // barrier #1 (staging complete)

    int l = t & 63, w = t >> 6;                // 4 waves, 9 pixel-tiles each
    int quad = l >> 4, rc = l & 15;

    // ---- phase 1: D(16co x 576px) = W1'(16x144)*im2col + bias1 ----
    f32x4 dreg[9];
    {
        int ci0 = (quad & 1) * 8;
        short8 afr[5];
#pragma unroll
        for (int kk = 0; kk < 5; kk++)
            afr[kk] = *(const short8*)&wAp[(kk*16 + rc)*40 + quad*8];
        f32x4 cb1 = *(const f32x4*)&bias1[quad*4];

        const int offE[5] = {0, 48, 648, 1248, 1296};     // taps 0,2,4,6,8
        const int offO[5] = {24, 624, 672, 1272, 1872};   // taps 1,3,5,7,9(A=0)
        int off[5];
#pragma unroll
        for (int kk = 0; kk < 5; kk++) off[kk] = (quad >= 2) ? offO[kk] : offE[kk];

#pragma unroll
        for (int tt = 0; tt < 9; tt++) {
            int s = (w*9 + tt)*16 + rc;
            int y = s / 24; int x = s - y*24;
            int base = (y*26 + x)*24 + ci0;
            f32x4 acc = cb1;
#pragma unroll
            for (int kk = 0; kk < 5; kk++) {
                short8 bf = *(const short8*)&xs[base + off[kk]];
                acc = __builtin_amdgcn_mfma_f32_16x16x32_bf16(afr[kk], bf, acc, 0, 0, 0);
            }
#pragma unroll
            for (int r = 0; r < 4; r++) acc[r] = fmaxf(acc[r], 0.f);
            dreg[tt] = acc;
        }
    }

    // h -> hsb (consumed by the SAME wave only; lgkmcnt orders it, no barrier)
    // + h1b global bf16 channel-major
    {
        unsigned short* hout = &h1b[((i*2 + b)*256 + g*16)*576];
#pragma unroll
        for (int tt = 0; tt < 9; tt++) {
            int s = (w*9 + tt)*16 + rc;
            f32x4 acc = dreg[tt];
            unsigned short e0 = f2bf(acc[0]), e1 = f2bf(acc[1]);
            unsigned short e2 = f2bf(acc[2]), e3 = f2bf(acc[3]);
            uint2 pk = {(unsigned)e0 | ((unsigned)e1 << 16),
                        (unsigned)e2 | ((unsigned)e3 << 16)};
            *(uint2*)&hsb[s*20 + quad*4] = pk;
            hout[(quad*4 + 0)*576 + s] = e0;
            hout[(quad*4 + 1)*576 + s] = e1;
            hout[(quad*4 + 2)*576 + s] = e2;
            hout[(quad*4 + 3)*576 + s] = e3;
        }
    }

    // ---- phase 2 (transposed, registered A): D2[s,m] = h(s,j)*W2'(j,m)+be[m]
    // A = own 9 h-tiles; B = W2 strip per mt. Pool = per-lane row-sum of relu
    // + 2 shfl -> LDS atomic pacc. ----
    {
        int q8 = (quad & 1) * 8;               // j-offset quads 0/1; 2/3 read zpad
        short8 af2[9];
#pragma unroll
        for (int u = 0; u < 9; u++) {
            int boff = (l < 32) ? (HS_OFF + (((w*9 + u)*16 + rc)*20 + q8)*2) : ZP_OFF;
            af2[u] = *(const short8*)(smem + boff);
        }
        for (int mt = 0; mt < 25; mt++) {
            int m0 = mt*16;
            int woff = (l < 32) ? (WLB_OFF + ((m0 + rc)*16 + q8)*2) : ZP_OFF;
            short8 wf = *(const short8*)(smem + woff);
            float be = bias2[m0 + rc];
            f32x4 cb = {be, be, be, be};       // bias per column m

            f32x4 accv = {0.f, 0.f, 0.f, 0.f};
#pragma unroll
            for (int u = 0; u < 9; u++) {
                f32x4 d = __builtin_amdgcn_mfma_f32_16x16x32_bf16(af2[u], wf, cb, 0, 0, 0);
#pragma unroll
                for (int r = 0; r < 4; r++)
                    accv[r] += fmaxf(d[r], 0.f);
            }
            float a = (accv[0] + accv[1]) + (accv[2] + accv[3]);
            a += __shfl_xor(a, 16);            // sum 4 quads = 16 rows per tile
            a += __shfl_xor(a, 32);
            if (l < 16)
                atomicAdd(&pacc[m0 + l], a);   // ds_add_f32, 4 waves per addr
        }
    }
    __syncthreads();                           // barrier #2 (pacc complete)

    const float inv = 1.f / 676.f;             // 26x26 pool incl. 100 border px
    for (int m = t; m < 400; m += 256) {
        float be = bias2[m];
        pooled[(i*2+b)*6400 + g*400 + m] =
            (pacc[m] + 100.f * fmaxf(be, 0.f)) * inv;
    }
}

// k3: aff per (i,b) — 32 blocks only (aff computed ONCE)
__global__ __launch_bounds__(256) void k3_aff(const float* __restrict__ pooled,
                                              float* __restrict__ aff)
{
    __shared__ float th[400];
    __shared__ float parts[256];
    int bid = blockIdx.x;           // i*2 + b
    int i = bid >> 1;
    int t = threadIdx.x;
    const float* pb = &pooled[bid*6400];
    for (int idx = t; idx < 400; idx += 256) th[idx] = pb[i*400 + idx];
    __syncthreads();
    int l = t >> 4, p = t & 15;
    float sum = 0.f;
    const float* pl = &pb[l*400];
    for (int m = p*25; m < p*25 + 25; m++) sum = fmaf(th[m], pl[m], sum);
    parts[t] = sum;
    __syncthreads();
    if (t < 16) {
        float s = 0.f;
        for (int pp = 0; pp < 16; pp++) s += parts[t*16 + pp];
        aff[bid*16 + t] = s * (1.f/16.f);
    }
}

// k4: output contraction over bf16 h, pair loads (uint = 2 px), float2 stores.
__global__ __launch_bounds__(256) void k4_out(const unsigned short* __restrict__ h1b,
                                              const float* __restrict__ aff,
                                              float* __restrict__ out)
{
    __shared__ float a0[16], a1[16];
    int bid = blockIdx.x;           // i*32 + q*16 + cg
    int i = bid >> 5, q = (bid >> 4) & 1, cg = bid & 15;
    int t = threadIdx.x;
    if (t < 16) a0[t] = aff[(i*2+0)*16 + t];
    else if (t < 32) a1[t-16] = aff[(i*2+1)*16 + (t-16)];
    __syncthreads();
    const unsigned short* hb = &h1b[((i*2+q)*256 + cg)*576];
    int ch = i*32 + q*16 + cg;
    for (int pp = t; pp < 288; pp += 256) {    // pixel pairs
        int s = pp*2;
        float acc0a = 0.f, acc0b = 0.f, acc1a = 0.f, acc1b = 0.f;
#pragma unroll
        for (int k = 0; k < 16; k++) {
            unsigned hv = *(const unsigned*)&hb[k*9216 + s];
            float va = __uint_as_float(hv << 16);
            float vb = __uint_as_float(hv & 0xffff0000u);
            acc0a = fmaf(a0[k], va, acc0a);
            acc0b = fmaf(a0[k], vb, acc0b);
            acc1a = fmaf(a1[k], va, acc1a);
            acc1b = fmaf(a1[k], vb, acc1b);
        }
        float2 o0 = {acc0a, acc0b};
        float2 o1 = {acc1a, acc1b};
        *(float2*)&out[ch*576 + s]         = o0;
        *(float2*)&out[(512 + ch)*576 + s] = o1;
    }
}

extern "C" void kernel_launch(void* const* d_in, const int* in_sizes, int n_in,
                              void* d_out, int out_size, void* d_ws, size_t ws_size,
                              hipStream_t stream)
{
    const float* x  = (const float*)d_in[0];
    const float* W1 = (const float*)d_in[1];
    const float* g1 = (const float*)d_in[2];
    const float* b1 = (const float*)d_in[3];
    const float* m1 = (const float*)d_in[4];
    const float* v1 = (const float*)d_in[5];
    const float* W2 = (const float*)d_in[6];
    const float* g2 = (const float*)d_in[7];
    const float* b2 = (const float*)d_in[8];
    const float* m2 = (const float*)d_in[9];
    const float* v2 = (const float*)d_in[10];

    unsigned short* h1b = (unsigned short*)d_ws;          // 4,718,592 ushorts
    float* pooled = (float*)(h1b + 16*2*256*576);         // 204,800 floats
    float* aff    = pooled + 204800;                      // 512 floats

    float* out = (float*)d_out;

    hipLaunchKernelGGL(k12_fused, dim3(512), dim3(256), 0, stream,
                       x, W1, g1, b1, m1, v1, W2, g2, b2, m2, v2, h1b, pooled);
    hipLaunchKernelGGL(k3_aff,    dim3(32),  dim3(256), 0, stream,
                       pooled, aff);
    hipLaunchKernelGGL(k4_out,    dim3(512), dim3(256), 0, stream,
                       h1b, aff, out);
}